// Round 6
// baseline (168.271 us; speedup 1.0000x reference)
//
#include <hip/hip_runtime.h>

// MetricBiasUpdater: B_next = clip(alpha*B_prev - beta*relu(pairdist(H@W^T)), -10, 10)
// B=4, N=2048, D=1024, K(geom)=32. Output fp32 [4,2048,2048].
//
// v7:
//  k0/k1: unchanged.
//  k2: pipelined across j-tiles. Evidence: occupancy 27% on a fully-resident
//      grid => avg wave lifetime ~26k cycles => serialized HBM round trips
//      (all v2-v6 variants compiled to load->use chains). Now each block owns
//      64(i) x 512(j) = 4 tiles; Bp loads are VOLATILE (cannot be reordered/
//      sunk) and double-buffered across tiles -> steady-state vmcnt(8..16),
//      never a drain. Gj/Qj staged once in LDS so MFMA operands ride lgkmcnt,
//      decoupled from the Bp vmcnt FIFO. out stored nontemporally.

typedef __attribute__((ext_vector_type(8))) short short8;   // 8 bf16 (4 VGPRs)
typedef __attribute__((ext_vector_type(4))) short short4v;  // 4 bf16 (2 VGPRs)
typedef __attribute__((ext_vector_type(4))) float floatx4;  // 4 fp32 (4 VGPRs)

static __device__ __forceinline__ short bf16_bits(float f) {
    union { float f; unsigned int u; } v; v.f = f;
    unsigned int u = v.u;
    u += 0x7FFFu + ((u >> 16) & 1u);   // round-to-nearest-even
    return (short)(u >> 16);
}

static __device__ __forceinline__ float bf16_to_f32(unsigned short h) {
    union { unsigned int u; float f; } v; v.u = ((unsigned int)h) << 16;
    return v.f;
}

// ---------------------------------------------------------------------------
// Kernel 0: W fp32 [32][1024] -> bf16.
// ---------------------------------------------------------------------------
__global__ __launch_bounds__(256) void k0_wcast(const float* __restrict__ W,
                                                short* __restrict__ Wb) {
    const int f = blockIdx.x * 256 + threadIdx.x;   // 8192 float4 chunks
    const float4 v = *(const float4*)(W + (long)f * 4);
    short4v s;
    s[0] = bf16_bits(v.x); s[1] = bf16_bits(v.y);
    s[2] = bf16_bits(v.z); s[3] = bf16_bits(v.w);
    *(short4v*)(Wb + (long)f * 4) = s;
}

// ---------------------------------------------------------------------------
// Kernel 1: G[row][k] = sum_d H[row][d] * W[k][d]  (rows = 8192 flat, k = 32)
// ---------------------------------------------------------------------------
__global__ __launch_bounds__(256) void k1_proj(const float* __restrict__ H,
                                               const short* __restrict__ Wb,
                                               unsigned short* __restrict__ G,
                                               float* __restrict__ Q) {
    const int blk  = blockIdx.x;        // 512 blocks x 16 rows
    const int t    = threadIdx.x;
    const int w    = t >> 6;            // wave id -> K quarter
    const int lane = t & 63;
    const int m    = lane & 15;         // A row within tile / B column n
    const int quad = lane >> 4;

    __shared__ short sH[16 * 1032];     // 16 rows x 1024 bf16, stride 1032 (33 KB)

    // ---- coalesced stage: 2048 8-float chunks, 8 per thread ----
    const float* Hb = H + (long)blk * 16384;
    #pragma unroll
    for (int it = 0; it < 8; ++it) {
        const int f  = t + it * 256;    // 0..2047
        const int r  = f >> 7;          // row 0..15
        const int c8 = f & 127;         // 8-float chunk within row
        const float4 v0 = *(const float4*)(Hb + r * 1024 + c8 * 8);
        const float4 v1 = *(const float4*)(Hb + r * 1024 + c8 * 8 + 4);
        short8 sv;
        sv[0] = bf16_bits(v0.x); sv[1] = bf16_bits(v0.y);
        sv[2] = bf16_bits(v0.z); sv[3] = bf16_bits(v0.w);
        sv[4] = bf16_bits(v1.x); sv[5] = bf16_bits(v1.y);
        sv[6] = bf16_bits(v1.z); sv[7] = bf16_bits(v1.w);
        *(short8*)&sH[r * 1032 + c8 * 8] = sv;
    }
    __syncthreads();

    const int kq = w * 256 + quad * 8;  // this lane's k base (frag: k = quad*8 + j)
    const short* wb0 = Wb + (long)m * 1024 + kq;          // n-tile 0: n = m
    const short* wb1 = Wb + (long)(m + 16) * 1024 + kq;   // n-tile 1: n = m+16

    floatx4 acc0 = {0.f, 0.f, 0.f, 0.f};
    floatx4 acc1 = {0.f, 0.f, 0.f, 0.f};

    short8 b0 = *(const short8*)wb0;
    short8 b1 = *(const short8*)wb1;

    #pragma unroll
    for (int s = 0; s < 8; ++s) {
        short8 nb0, nb1;
        if (s < 7) {                    // prefetch next W-step while MFMA runs
            nb0 = *(const short8*)(wb0 + (s + 1) * 32);
            nb1 = *(const short8*)(wb1 + (s + 1) * 32);
        }
        const short8 af = *(const short8*)&sH[m * 1032 + kq + s * 32];
        acc0 = __builtin_amdgcn_mfma_f32_16x16x32_bf16(af, b0, acc0, 0, 0, 0);
        acc1 = __builtin_amdgcn_mfma_f32_16x16x32_bf16(af, b1, acc1, 0, 0, 0);
        if (s < 7) { b0 = nb0; b1 = nb1; }
    }

    // reduce K-quarter partials across the 4 waves.
    // C/D layout: col = lane&15 (=n), row = quad*4 + reg (=m)  (measured m89)
    __shared__ float red[4][16][32];
    #pragma unroll
    for (int r = 0; r < 4; ++r) {
        red[w][quad * 4 + r][m]      = acc0[r];
        red[w][quad * 4 + r][m + 16] = acc1[r];
    }
    __syncthreads();
    for (int e = t; e < 512; e += 256) {
        const int mm = e >> 5, nn = e & 31;
        float v = red[0][mm][nn] + red[1][mm][nn] + red[2][mm][nn] + red[3][mm][nn];
        const unsigned short hb = (unsigned short)bf16_bits(v);
        G[(long)(blk * 16 + mm) * 32 + nn] = hb;
        red[0][mm][nn] = bf16_to_f32(hb);   // Q from ROUNDED values: dist(i,i) ~ 0
    }
    __syncthreads();
    if (t < 16) {
        float s = 0.f;
        #pragma unroll
        for (int nn = 0; nn < 32; ++nn) { const float v = red[0][t][nn]; s += v * v; }
        Q[blk * 16 + t] = s;
    }
}

// ---------------------------------------------------------------------------
// Kernel 2: out[b][i][j] = clip(alpha*Bp - beta*relu(q[i]+q[j]-2*G[i].G[j]))
// Block = 64(i) x 512(j) = 4 j-tiles, 4 waves (wave w owns i rows w*16..+16).
// Gj (512 rows) + Qj staged ONCE in LDS (lgkmcnt path). Bp loads volatile,
// double-buffered across tiles (vmcnt path, steady-state vmcnt(8..16)).
// Stores nontemporal. Grid 512 blocks = 2 blocks/CU fully resident.
// ---------------------------------------------------------------------------
__global__ __launch_bounds__(256) void k2_update(const float* __restrict__ Bp,
                                                 const unsigned short* __restrict__ G,
                                                 const float* __restrict__ Q,
                                                 const float* __restrict__ alphap,
                                                 const float* __restrict__ betap,
                                                 float* __restrict__ out) {
    __shared__ short sGj[512 * 40];   // 512 rows x 32 bf16, stride 40 (80 B) = 40 KB
    __shared__ float sQj[512];        // 2 KB

    const int b  = blockIdx.z;
    const int i0 = blockIdx.y * 64;
    const int J0 = blockIdx.x * 512;
    const int t  = threadIdx.x;
    const int w    = t >> 6;
    const int lane = t & 63;
    const int m    = lane & 15;       // i within wave tile (D column)
    const int quad = lane >> 4;       // j sub-quad (D row group)

    const int i = i0 + w * 16 + m;
    const long rowbase = ((long)b * 2048 + i) * 2048;
    const float* bprow = Bp  + rowbase + J0;
    float*       orow  = out + rowbase + J0;

    floatx4 bvA[8], bvB[8];

// issue 8 volatile dwordx4 Bp loads for tile T into BANK (program-ordered)
#define BP_ISSUE(BANK, T) { \
    volatile const floatx4* p_ = (volatile const floatx4*)(bprow + (T) * 128); \
    _Pragma("unroll") \
    for (int jt = 0; jt < 8; ++jt) BANK[jt] = p_[jt * 4 + quad]; }

// MFMA + fused epilogue + NT stores for tile T consuming BANK
#define DO_TILE(BANK, T) { \
    short8 afj_[8]; floatx4 qjv_[8]; \
    _Pragma("unroll") \
    for (int jt = 0; jt < 8; ++jt) { \
        afj_[jt] = *(const short8*)&sGj[((T) * 128 + jt * 16 + m) * 40 + quad * 8]; \
        qjv_[jt] = *(const floatx4*)&sQj[(T) * 128 + jt * 16 + quad * 4]; \
    } \
    floatx4 acc_[8]; \
    _Pragma("unroll") \
    for (int jt = 0; jt < 8; ++jt) { \
        floatx4 z_ = {0.f, 0.f, 0.f, 0.f}; \
        acc_[jt] = __builtin_amdgcn_mfma_f32_16x16x32_bf16(afj_[jt], bfi, z_, 0, 0, 0); \
    } \
    _Pragma("unroll") \
    for (int jt = 0; jt < 8; ++jt) { \
        floatx4 ov_; \
        _Pragma("unroll") \
        for (int r = 0; r < 4; ++r) { \
            float d_ = qi + qjv_[jt][r] - 2.f * acc_[jt][r]; \
            d_ = fmaxf(d_, 0.f); \
            ov_[r] = fminf(fmaxf(alpha * BANK[jt][r] - beta * d_, -10.f), 10.f); \
        } \
        __builtin_nontemporal_store(ov_, (floatx4*)(orow + (T) * 128 + (jt * 4 + quad) * 4)); \
    } }

    // ---- prologue: tile-0 Bp loads in flight during LDS staging ----
    BP_ISSUE(bvA, 0);

    // ---- stage Gj (512 rows x 64B) + Qj once ----
    const short* Gg = (const short*)G;
    #pragma unroll
    for (int l = 0; l < 8; ++l) {
        const int f = t + l * 256;        // 2048 16B-chunks
        const int r = f >> 2, c = f & 3;
        *(short8*)&sGj[r * 40 + c * 8] =
            *(const short8*)&Gg[(long)(b * 2048 + J0 + r) * 32 + c * 8];
    }
    sQj[t]       = Q[b * 2048 + J0 + t];
    sQj[t + 256] = Q[b * 2048 + J0 + 256 + t];
    __syncthreads();

    // per-wave invariants: Gi fragment (L2-hot) + scalars
    const short8 bfi = *(const short8*)&Gg[((long)(b * 2048 + i)) * 32 + quad * 8];
    const float qi    = Q[b * 2048 + i];
    const float alpha = alphap[0];
    const float beta  = betap[0];

    // ---- software pipeline: issue T+1 before computing T ----
    BP_ISSUE(bvB, 1);
    DO_TILE(bvA, 0);
    BP_ISSUE(bvA, 2);
    DO_TILE(bvB, 1);
    BP_ISSUE(bvB, 3);
    DO_TILE(bvA, 2);
    DO_TILE(bvB, 3);

#undef BP_ISSUE
#undef DO_TILE
}

extern "C" void kernel_launch(void* const* d_in, const int* in_sizes, int n_in,
                              void* d_out, int out_size, void* d_ws, size_t ws_size,
                              hipStream_t stream) {
    const float* H     = (const float*)d_in[0];   // [4,2048,1024]
    const float* Bp    = (const float*)d_in[1];   // [4,2048,2048]
    const float* W     = (const float*)d_in[2];   // [32,1024]
    const float* alpha = (const float*)d_in[3];
    const float* beta  = (const float*)d_in[4];
    float* out = (float*)d_out;

    unsigned short* G = (unsigned short*)d_ws;          // [8192][32] bf16 = 512 KB
    float* Q  = (float*)((char*)d_ws + 8192 * 32 * 2);  // [8192] fp32 = 32 KB
    short* Wb = (short*)((char*)d_ws + 8192 * 32 * 2 + 8192 * 4);  // [32][1024] bf16

    k0_wcast<<<32, 256, 0, stream>>>(W, Wb);
    k1_proj<<<512, 256, 0, stream>>>(H, Wb, G, Q);

    dim3 g2(4, 32, 4);                // j-spans(512), i-tiles(64), batch
    k2_update<<<g2, 256, 0, stream>>>(Bp, G, Q, alpha, beta, out);
}

// Round 7
// 161.115 us; speedup vs baseline: 1.0444x; 1.0444x over previous
//
#include <hip/hip_runtime.h>

// MetricBiasUpdater: B_next = clip(alpha*B_prev - beta*relu(pairdist(H@W^T)), -10, 10)
// B=4, N=2048, D=1024, K(geom)=32. Output fp32 [4,2048,2048].
//
// v8:
//  k0/k1: unchanged.
//  k2: ALL loads hand-rolled as inline-asm global_load_dwordx4. Evidence from
//      v2-v7: C++-level loads always compile to serial load->use chains (the
//      IR sinks readonly loads; volatile serializes; per-value anchors become
//      interleaved wait points). 26 asm-volatile loads issue back-to-back
//      (asm volatile keeps mutual program order), then ONE s_waitcnt vmcnt(0)
//      + sched_barrier(0)  -> one latency exposure per wave instead of ~17.
//      No LDS, no barriers, no volatile, no NT stores.

typedef __attribute__((ext_vector_type(8))) short short8;   // 8 bf16 (4 VGPRs)
typedef __attribute__((ext_vector_type(4))) short short4v;  // 4 bf16 (2 VGPRs)
typedef __attribute__((ext_vector_type(4))) float floatx4;  // 4 fp32 (4 VGPRs)

static __device__ __forceinline__ short bf16_bits(float f) {
    union { float f; unsigned int u; } v; v.f = f;
    unsigned int u = v.u;
    u += 0x7FFFu + ((u >> 16) & 1u);   // round-to-nearest-even
    return (short)(u >> 16);
}

static __device__ __forceinline__ float bf16_to_f32(unsigned short h) {
    union { unsigned int u; float f; } v; v.u = ((unsigned int)h) << 16;
    return v.f;
}

// ---------------------------------------------------------------------------
// Kernel 0: W fp32 [32][1024] -> bf16.
// ---------------------------------------------------------------------------
__global__ __launch_bounds__(256) void k0_wcast(const float* __restrict__ W,
                                                short* __restrict__ Wb) {
    const int f = blockIdx.x * 256 + threadIdx.x;   // 8192 float4 chunks
    const float4 v = *(const float4*)(W + (long)f * 4);
    short4v s;
    s[0] = bf16_bits(v.x); s[1] = bf16_bits(v.y);
    s[2] = bf16_bits(v.z); s[3] = bf16_bits(v.w);
    *(short4v*)(Wb + (long)f * 4) = s;
}

// ---------------------------------------------------------------------------
// Kernel 1: G[row][k] = sum_d H[row][d] * W[k][d]  (rows = 8192 flat, k = 32)
// ---------------------------------------------------------------------------
__global__ __launch_bounds__(256) void k1_proj(const float* __restrict__ H,
                                               const short* __restrict__ Wb,
                                               unsigned short* __restrict__ G,
                                               float* __restrict__ Q) {
    const int blk  = blockIdx.x;        // 512 blocks x 16 rows
    const int t    = threadIdx.x;
    const int w    = t >> 6;            // wave id -> K quarter
    const int lane = t & 63;
    const int m    = lane & 15;         // A row within tile / B column n
    const int quad = lane >> 4;

    __shared__ short sH[16 * 1032];     // 16 rows x 1024 bf16, stride 1032 (33 KB)

    // ---- coalesced stage: 2048 8-float chunks, 8 per thread ----
    const float* Hb = H + (long)blk * 16384;
    #pragma unroll
    for (int it = 0; it < 8; ++it) {
        const int f  = t + it * 256;    // 0..2047
        const int r  = f >> 7;          // row 0..15
        const int c8 = f & 127;         // 8-float chunk within row
        const float4 v0 = *(const float4*)(Hb + r * 1024 + c8 * 8);
        const float4 v1 = *(const float4*)(Hb + r * 1024 + c8 * 8 + 4);
        short8 sv;
        sv[0] = bf16_bits(v0.x); sv[1] = bf16_bits(v0.y);
        sv[2] = bf16_bits(v0.z); sv[3] = bf16_bits(v0.w);
        sv[4] = bf16_bits(v1.x); sv[5] = bf16_bits(v1.y);
        sv[6] = bf16_bits(v1.z); sv[7] = bf16_bits(v1.w);
        *(short8*)&sH[r * 1032 + c8 * 8] = sv;
    }
    __syncthreads();

    const int kq = w * 256 + quad * 8;  // this lane's k base (frag: k = quad*8 + j)
    const short* wb0 = Wb + (long)m * 1024 + kq;          // n-tile 0: n = m
    const short* wb1 = Wb + (long)(m + 16) * 1024 + kq;   // n-tile 1: n = m+16

    floatx4 acc0 = {0.f, 0.f, 0.f, 0.f};
    floatx4 acc1 = {0.f, 0.f, 0.f, 0.f};

    short8 b0 = *(const short8*)wb0;
    short8 b1 = *(const short8*)wb1;

    #pragma unroll
    for (int s = 0; s < 8; ++s) {
        short8 nb0, nb1;
        if (s < 7) {                    // prefetch next W-step while MFMA runs
            nb0 = *(const short8*)(wb0 + (s + 1) * 32);
            nb1 = *(const short8*)(wb1 + (s + 1) * 32);
        }
        const short8 af = *(const short8*)&sH[m * 1032 + kq + s * 32];
        acc0 = __builtin_amdgcn_mfma_f32_16x16x32_bf16(af, b0, acc0, 0, 0, 0);
        acc1 = __builtin_amdgcn_mfma_f32_16x16x32_bf16(af, b1, acc1, 0, 0, 0);
        if (s < 7) { b0 = nb0; b1 = nb1; }
    }

    // reduce K-quarter partials across the 4 waves.
    // C/D layout: col = lane&15 (=n), row = quad*4 + reg (=m)  (measured m89)
    __shared__ float red[4][16][32];
    #pragma unroll
    for (int r = 0; r < 4; ++r) {
        red[w][quad * 4 + r][m]      = acc0[r];
        red[w][quad * 4 + r][m + 16] = acc1[r];
    }
    __syncthreads();
    for (int e = t; e < 512; e += 256) {
        const int mm = e >> 5, nn = e & 31;
        float v = red[0][mm][nn] + red[1][mm][nn] + red[2][mm][nn] + red[3][mm][nn];
        const unsigned short hb = (unsigned short)bf16_bits(v);
        G[(long)(blk * 16 + mm) * 32 + nn] = hb;
        red[0][mm][nn] = bf16_to_f32(hb);   // Q from ROUNDED values: dist(i,i) ~ 0
    }
    __syncthreads();
    if (t < 16) {
        float s = 0.f;
        #pragma unroll
        for (int nn = 0; nn < 32; ++nn) { const float v = red[0][t][nn]; s += v * v; }
        Q[blk * 16 + t] = s;
    }
}

// ---------------------------------------------------------------------------
// Kernel 2: out[b][i][j] = clip(alpha*Bp - beta*relu(q[i]+q[j]-2*G[i].G[j]))
// 64(i) x 128(j) per block, 4 waves, no LDS, no barriers.
// Phase 1: 26 inline-asm global_load_dwordx4, issued back-to-back.
// Phase 2: single s_waitcnt vmcnt(0) + sched_barrier(0).
// Phase 3: 8x mfma(Gj_frag, Gi_frag) -> D row = j (consecutive), col = i;
//          fused epilogue, 8x dwordx4 stores.
// ---------------------------------------------------------------------------
__global__ __launch_bounds__(256) void k2_update(const float* __restrict__ Bp,
                                                 const unsigned short* __restrict__ G,
                                                 const float* __restrict__ Q,
                                                 const float* __restrict__ alphap,
                                                 const float* __restrict__ betap,
                                                 float* __restrict__ out) {
    const int b  = blockIdx.z;
    const int i0 = blockIdx.y * 64;
    const int j0 = blockIdx.x * 128;
    const int t  = threadIdx.x;
    const int w    = t >> 6;          // wave -> i rows [w*16, w*16+16)
    const int lane = t & 63;
    const int m    = lane & 15;       // i within wave tile (D column)
    const int quad = lane >> 4;       // j sub-quad (D row group)

    const int i = i0 + w * 16 + m;
    const long rowoff = ((long)b * 2048 + i) * 2048 + j0;

    const float* bpp = Bp + rowoff + quad * 4;                   // bv[jt]: byte jt*64
    const short* Gg  = (const short*)G;
    const short* gjp  = Gg + ((long)(b * 2048 + j0 + m)) * 32 + quad * 8;  // afj[jt]: byte jt*1024
    const short* gjp2 = gjp + 4 * 512;
    const short* gip  = Gg + ((long)(b * 2048 + i)) * 32 + quad * 8;
    const float* qjp  = Q + (long)b * 2048 + j0 + quad * 4;      // qjv[jt]: byte jt*64
    const float* qip  = Q + (long)b * 2048 + i;

    floatx4 bv0, bv1, bv2, bv3, bv4, bv5, bv6, bv7;
    short8  af0, af1, af2, af3, af4, af5, af6, af7, bfi;
    floatx4 qj0, qj1, qj2, qj3, qj4, qj5, qj6, qj7;
    float   qi;

    // ---- phase 1: issue all 26 loads back-to-back (asm volatile order) ----
#define LD4F(dst, base, off) \
    asm volatile("global_load_dwordx4 %0, %1, off offset:" #off : "=v"(dst) : "v"(base))
    LD4F(bv0, bpp, 0);   LD4F(bv1, bpp, 64);  LD4F(bv2, bpp, 128); LD4F(bv3, bpp, 192);
    LD4F(bv4, bpp, 256); LD4F(bv5, bpp, 320); LD4F(bv6, bpp, 384); LD4F(bv7, bpp, 448);
    LD4F(af0, gjp, 0);   LD4F(af1, gjp, 1024);  LD4F(af2, gjp, 2048);  LD4F(af3, gjp, 3072);
    LD4F(af4, gjp2, 0);  LD4F(af5, gjp2, 1024); LD4F(af6, gjp2, 2048); LD4F(af7, gjp2, 3072);
    LD4F(bfi, gip, 0);
    LD4F(qj0, qjp, 0);   LD4F(qj1, qjp, 64);  LD4F(qj2, qjp, 128); LD4F(qj3, qjp, 192);
    LD4F(qj4, qjp, 256); LD4F(qj5, qjp, 320); LD4F(qj6, qjp, 384); LD4F(qj7, qjp, 448);
    asm volatile("global_load_dword %0, %1, off" : "=v"(qi) : "v"(qip));
#undef LD4F

    const float alpha = alphap[0];
    const float beta  = betap[0];

    // ---- phase 2: ONE drain, fenced against hoisting (rule #18) ----
    asm volatile("s_waitcnt vmcnt(0)" ::: "memory");
    __builtin_amdgcn_sched_barrier(0);

    // ---- phase 3: MFMA + fused epilogue ----
    // acc[jt] = mfma(Gj_frag, Gi_frag): D row = quad*4+r = j local, col = m = i
    floatx4 z = {0.f, 0.f, 0.f, 0.f};
    floatx4 acc0 = __builtin_amdgcn_mfma_f32_16x16x32_bf16(af0, bfi, z, 0, 0, 0);
    floatx4 acc1 = __builtin_amdgcn_mfma_f32_16x16x32_bf16(af1, bfi, z, 0, 0, 0);
    floatx4 acc2 = __builtin_amdgcn_mfma_f32_16x16x32_bf16(af2, bfi, z, 0, 0, 0);
    floatx4 acc3 = __builtin_amdgcn_mfma_f32_16x16x32_bf16(af3, bfi, z, 0, 0, 0);
    floatx4 acc4 = __builtin_amdgcn_mfma_f32_16x16x32_bf16(af4, bfi, z, 0, 0, 0);
    floatx4 acc5 = __builtin_amdgcn_mfma_f32_16x16x32_bf16(af5, bfi, z, 0, 0, 0);
    floatx4 acc6 = __builtin_amdgcn_mfma_f32_16x16x32_bf16(af6, bfi, z, 0, 0, 0);
    floatx4 acc7 = __builtin_amdgcn_mfma_f32_16x16x32_bf16(af7, bfi, z, 0, 0, 0);

    float* op = out + rowoff + quad * 4;

#define EPI(jt, ACC, QJ, BV) { \
    floatx4 ov_; \
    _Pragma("unroll") \
    for (int r = 0; r < 4; ++r) { \
        float d_ = qi + QJ[r] - 2.f * ACC[r]; \
        d_ = fmaxf(d_, 0.f); \
        ov_[r] = fminf(fmaxf(alpha * BV[r] - beta * d_, -10.f), 10.f); \
    } \
    *(floatx4*)(op + (jt) * 16) = ov_; }
    EPI(0, acc0, qj0, bv0); EPI(1, acc1, qj1, bv1);
    EPI(2, acc2, qj2, bv2); EPI(3, acc3, qj3, bv3);
    EPI(4, acc4, qj4, bv4); EPI(5, acc5, qj5, bv5);
    EPI(6, acc6, qj6, bv6); EPI(7, acc7, qj7, bv7);
#undef EPI
}

extern "C" void kernel_launch(void* const* d_in, const int* in_sizes, int n_in,
                              void* d_out, int out_size, void* d_ws, size_t ws_size,
                              hipStream_t stream) {
    const float* H     = (const float*)d_in[0];   // [4,2048,1024]
    const float* Bp    = (const float*)d_in[1];   // [4,2048,2048]
    const float* W     = (const float*)d_in[2];   // [32,1024]
    const float* alpha = (const float*)d_in[3];
    const float* beta  = (const float*)d_in[4];
    float* out = (float*)d_out;

    unsigned short* G = (unsigned short*)d_ws;          // [8192][32] bf16 = 512 KB
    float* Q  = (float*)((char*)d_ws + 8192 * 32 * 2);  // [8192] fp32 = 32 KB
    short* Wb = (short*)((char*)d_ws + 8192 * 32 * 2 + 8192 * 4);  // [32][1024] bf16

    k0_wcast<<<32, 256, 0, stream>>>(W, Wb);
    k1_proj<<<512, 256, 0, stream>>>(H, Wb, G, Q);

    dim3 g2(16, 32, 4);               // j-tiles(128), i-tiles(64), batch
    k2_update<<<g2, 256, 0, stream>>>(Bp, G, Q, alpha, beta, out);
}

// Round 8
// 159.324 us; speedup vs baseline: 1.0562x; 1.0112x over previous
//
#include <hip/hip_runtime.h>

// MetricBiasUpdater: B_next = clip(alpha*B_prev - beta*relu(pairdist(H@W^T)), -10, 10)
// B=4, N=2048, D=1024, K(geom)=32. Output fp32 [4,2048,2048].
//
// v9:
//  k0/k1: unchanged.
//  k2: 512 long-lived blocks (2/CU, fully resident) each looping 4 j-tiles,
//      instead of 2048 short blocks: v2-v8's 40 us was body-independent
//      (occupancy 27% on a machine-filling grid => CUs starved for blocks,
//      dispatch/teardown bound). Inner body = v8's asm-batched loads
//      (26 back-to-back global_load_dwordx4, ONE vmcnt drain per tile).
//      __launch_bounds__(256,2) grants 256 VGPRs so the batch stays in
//      arch VGPRs (v8's 64-VGPR budget forced AGPR-copy serialization).

typedef __attribute__((ext_vector_type(8))) short short8;   // 8 bf16 (4 VGPRs)
typedef __attribute__((ext_vector_type(4))) short short4v;  // 4 bf16 (2 VGPRs)
typedef __attribute__((ext_vector_type(4))) float floatx4;  // 4 fp32 (4 VGPRs)

static __device__ __forceinline__ short bf16_bits(float f) {
    union { float f; unsigned int u; } v; v.f = f;
    unsigned int u = v.u;
    u += 0x7FFFu + ((u >> 16) & 1u);   // round-to-nearest-even
    return (short)(u >> 16);
}

static __device__ __forceinline__ float bf16_to_f32(unsigned short h) {
    union { unsigned int u; float f; } v; v.u = ((unsigned int)h) << 16;
    return v.f;
}

// ---------------------------------------------------------------------------
// Kernel 0: W fp32 [32][1024] -> bf16.
// ---------------------------------------------------------------------------
__global__ __launch_bounds__(256) void k0_wcast(const float* __restrict__ W,
                                                short* __restrict__ Wb) {
    const int f = blockIdx.x * 256 + threadIdx.x;   // 8192 float4 chunks
    const float4 v = *(const float4*)(W + (long)f * 4);
    short4v s;
    s[0] = bf16_bits(v.x); s[1] = bf16_bits(v.y);
    s[2] = bf16_bits(v.z); s[3] = bf16_bits(v.w);
    *(short4v*)(Wb + (long)f * 4) = s;
}

// ---------------------------------------------------------------------------
// Kernel 1: G[row][k] = sum_d H[row][d] * W[k][d]  (rows = 8192 flat, k = 32)
// ---------------------------------------------------------------------------
__global__ __launch_bounds__(256) void k1_proj(const float* __restrict__ H,
                                               const short* __restrict__ Wb,
                                               unsigned short* __restrict__ G,
                                               float* __restrict__ Q) {
    const int blk  = blockIdx.x;        // 512 blocks x 16 rows
    const int t    = threadIdx.x;
    const int w    = t >> 6;            // wave id -> K quarter
    const int lane = t & 63;
    const int m    = lane & 15;         // A row within tile / B column n
    const int quad = lane >> 4;

    __shared__ short sH[16 * 1032];     // 16 rows x 1024 bf16, stride 1032 (33 KB)

    // ---- coalesced stage: 2048 8-float chunks, 8 per thread ----
    const float* Hb = H + (long)blk * 16384;
    #pragma unroll
    for (int it = 0; it < 8; ++it) {
        const int f  = t + it * 256;    // 0..2047
        const int r  = f >> 7;          // row 0..15
        const int c8 = f & 127;         // 8-float chunk within row
        const float4 v0 = *(const float4*)(Hb + r * 1024 + c8 * 8);
        const float4 v1 = *(const float4*)(Hb + r * 1024 + c8 * 8 + 4);
        short8 sv;
        sv[0] = bf16_bits(v0.x); sv[1] = bf16_bits(v0.y);
        sv[2] = bf16_bits(v0.z); sv[3] = bf16_bits(v0.w);
        sv[4] = bf16_bits(v1.x); sv[5] = bf16_bits(v1.y);
        sv[6] = bf16_bits(v1.z); sv[7] = bf16_bits(v1.w);
        *(short8*)&sH[r * 1032 + c8 * 8] = sv;
    }
    __syncthreads();

    const int kq = w * 256 + quad * 8;  // this lane's k base (frag: k = quad*8 + j)
    const short* wb0 = Wb + (long)m * 1024 + kq;          // n-tile 0: n = m
    const short* wb1 = Wb + (long)(m + 16) * 1024 + kq;   // n-tile 1: n = m+16

    floatx4 acc0 = {0.f, 0.f, 0.f, 0.f};
    floatx4 acc1 = {0.f, 0.f, 0.f, 0.f};

    short8 b0 = *(const short8*)wb0;
    short8 b1 = *(const short8*)wb1;

    #pragma unroll
    for (int s = 0; s < 8; ++s) {
        short8 nb0, nb1;
        if (s < 7) {                    // prefetch next W-step while MFMA runs
            nb0 = *(const short8*)(wb0 + (s + 1) * 32);
            nb1 = *(const short8*)(wb1 + (s + 1) * 32);
        }
        const short8 af = *(const short8*)&sH[m * 1032 + kq + s * 32];
        acc0 = __builtin_amdgcn_mfma_f32_16x16x32_bf16(af, b0, acc0, 0, 0, 0);
        acc1 = __builtin_amdgcn_mfma_f32_16x16x32_bf16(af, b1, acc1, 0, 0, 0);
        if (s < 7) { b0 = nb0; b1 = nb1; }
    }

    // reduce K-quarter partials across the 4 waves.
    // C/D layout: col = lane&15 (=n), row = quad*4 + reg (=m)  (measured m89)
    __shared__ float red[4][16][32];
    #pragma unroll
    for (int r = 0; r < 4; ++r) {
        red[w][quad * 4 + r][m]      = acc0[r];
        red[w][quad * 4 + r][m + 16] = acc1[r];
    }
    __syncthreads();
    for (int e = t; e < 512; e += 256) {
        const int mm = e >> 5, nn = e & 31;
        float v = red[0][mm][nn] + red[1][mm][nn] + red[2][mm][nn] + red[3][mm][nn];
        const unsigned short hb = (unsigned short)bf16_bits(v);
        G[(long)(blk * 16 + mm) * 32 + nn] = hb;
        red[0][mm][nn] = bf16_to_f32(hb);   // Q from ROUNDED values: dist(i,i) ~ 0
    }
    __syncthreads();
    if (t < 16) {
        float s = 0.f;
        #pragma unroll
        for (int nn = 0; nn < 32; ++nn) { const float v = red[0][t][nn]; s += v * v; }
        Q[blk * 16 + t] = s;
    }
}

// ---------------------------------------------------------------------------
// Kernel 2: out[b][i][j] = clip(alpha*Bp - beta*relu(q[i]+q[j]-2*G[i].G[j]))
// 512 blocks (2/CU, fully resident). Block = 64(i) x 512(j); loops 4 j-tiles
// of 64x128. Per tile: 24 inline-asm global_load_dwordx4 issued back-to-back,
// one s_waitcnt vmcnt(0) + sched_barrier(0), 8x mfma(Gj,Gi), fused epilogue.
// ---------------------------------------------------------------------------
__global__ __launch_bounds__(256, 2) void k2_update(const float* __restrict__ Bp,
                                                    const unsigned short* __restrict__ G,
                                                    const float* __restrict__ Q,
                                                    const float* __restrict__ alphap,
                                                    const float* __restrict__ betap,
                                                    float* __restrict__ out) {
    const int b  = blockIdx.z;
    const int i0 = blockIdx.y * 64;
    const int jx = blockIdx.x;        // j-span: [jx*512, jx*512+512)
    const int t  = threadIdx.x;
    const int w    = t >> 6;          // wave -> i rows [w*16, w*16+16)
    const int lane = t & 63;
    const int m    = lane & 15;       // i within wave tile (D column)
    const int quad = lane >> 4;       // j sub-quad (D row group)

    const int i = i0 + w * 16 + m;
    const long rowoff = ((long)b * 2048 + i) * 2048 + jx * 512;

    const short* Gg  = (const short*)G;
    const short* gip = Gg + ((long)(b * 2048 + i)) * 32 + quad * 8;
    const float* qip = Q + (long)b * 2048 + i;

    // tile-invariant: Gi fragment + qi (drained by first tile's waitcnt)
    short8 bfi; float qi;
    asm volatile("global_load_dwordx4 %0, %1, off" : "=v"(bfi) : "v"(gip));
    asm volatile("global_load_dword   %0, %1, off" : "=v"(qi)  : "v"(qip));

    const float alpha = alphap[0];
    const float beta  = betap[0];

#define LD4F(dst, base, off) \
    asm volatile("global_load_dwordx4 %0, %1, off offset:" #off : "=v"(dst) : "v"(base))

    #pragma unroll
    for (int it = 0; it < 4; ++it) {
        const float* bpp  = Bp + rowoff + it * 128 + quad * 4;   // bv[jt]: byte jt*64
        const short* gjp  = Gg + ((long)(b * 2048 + jx * 512 + it * 128 + m)) * 32 + quad * 8;
        const short* gjp2 = gjp + 64 * 32;                       // +64 G rows
        const float* qjp  = Q + (long)b * 2048 + jx * 512 + it * 128 + quad * 4;

        floatx4 bv0, bv1, bv2, bv3, bv4, bv5, bv6, bv7;
        short8  af0, af1, af2, af3, af4, af5, af6, af7;
        floatx4 qj0, qj1, qj2, qj3, qj4, qj5, qj6, qj7;

        // ---- issue all 24 tile loads back-to-back (asm program order) ----
        LD4F(bv0, bpp, 0);   LD4F(bv1, bpp, 64);  LD4F(bv2, bpp, 128); LD4F(bv3, bpp, 192);
        LD4F(bv4, bpp, 256); LD4F(bv5, bpp, 320); LD4F(bv6, bpp, 384); LD4F(bv7, bpp, 448);
        LD4F(af0, gjp, 0);   LD4F(af1, gjp, 1024);  LD4F(af2, gjp, 2048);  LD4F(af3, gjp, 3072);
        LD4F(af4, gjp2, 0);  LD4F(af5, gjp2, 1024); LD4F(af6, gjp2, 2048); LD4F(af7, gjp2, 3072);
        LD4F(qj0, qjp, 0);   LD4F(qj1, qjp, 64);  LD4F(qj2, qjp, 128); LD4F(qj3, qjp, 192);
        LD4F(qj4, qjp, 256); LD4F(qj5, qjp, 320); LD4F(qj6, qjp, 384); LD4F(qj7, qjp, 448);

        // ---- ONE drain, fenced against MFMA hoisting (rule #18) ----
        asm volatile("s_waitcnt vmcnt(0)" ::: "memory");
        __builtin_amdgcn_sched_barrier(0);

        // ---- MFMA: acc[jt] = mfma(Gj, Gi): D row = quad*4+r = j, col = m = i
        floatx4 z = {0.f, 0.f, 0.f, 0.f};
        floatx4 acc0 = __builtin_amdgcn_mfma_f32_16x16x32_bf16(af0, bfi, z, 0, 0, 0);
        floatx4 acc1 = __builtin_amdgcn_mfma_f32_16x16x32_bf16(af1, bfi, z, 0, 0, 0);
        floatx4 acc2 = __builtin_amdgcn_mfma_f32_16x16x32_bf16(af2, bfi, z, 0, 0, 0);
        floatx4 acc3 = __builtin_amdgcn_mfma_f32_16x16x32_bf16(af3, bfi, z, 0, 0, 0);
        floatx4 acc4 = __builtin_amdgcn_mfma_f32_16x16x32_bf16(af4, bfi, z, 0, 0, 0);
        floatx4 acc5 = __builtin_amdgcn_mfma_f32_16x16x32_bf16(af5, bfi, z, 0, 0, 0);
        floatx4 acc6 = __builtin_amdgcn_mfma_f32_16x16x32_bf16(af6, bfi, z, 0, 0, 0);
        floatx4 acc7 = __builtin_amdgcn_mfma_f32_16x16x32_bf16(af7, bfi, z, 0, 0, 0);

        float* op = out + rowoff + it * 128 + quad * 4;

#define EPI(jt, ACC, QJ, BV) { \
        floatx4 ov_; \
        _Pragma("unroll") \
        for (int r = 0; r < 4; ++r) { \
            float d_ = qi + QJ[r] - 2.f * ACC[r]; \
            d_ = fmaxf(d_, 0.f); \
            ov_[r] = fminf(fmaxf(alpha * BV[r] - beta * d_, -10.f), 10.f); \
        } \
        *(floatx4*)(op + (jt) * 16) = ov_; }
        EPI(0, acc0, qj0, bv0); EPI(1, acc1, qj1, bv1);
        EPI(2, acc2, qj2, bv2); EPI(3, acc3, qj3, bv3);
        EPI(4, acc4, qj4, bv4); EPI(5, acc5, qj5, bv5);
        EPI(6, acc6, qj6, bv6); EPI(7, acc7, qj7, bv7);
#undef EPI
    }
#undef LD4F
}

extern "C" void kernel_launch(void* const* d_in, const int* in_sizes, int n_in,
                              void* d_out, int out_size, void* d_ws, size_t ws_size,
                              hipStream_t stream) {
    const float* H     = (const float*)d_in[0];   // [4,2048,1024]
    const float* Bp    = (const float*)d_in[1];   // [4,2048,2048]
    const float* W     = (const float*)d_in[2];   // [32,1024]
    const float* alpha = (const float*)d_in[3];
    const float* beta  = (const float*)d_in[4];
    float* out = (float*)d_out;

    unsigned short* G = (unsigned short*)d_ws;          // [8192][32] bf16 = 512 KB
    float* Q  = (float*)((char*)d_ws + 8192 * 32 * 2);  // [8192] fp32 = 32 KB
    short* Wb = (short*)((char*)d_ws + 8192 * 32 * 2 + 8192 * 4);  // [32][1024] bf16

    k0_wcast<<<32, 256, 0, stream>>>(W, Wb);
    k1_proj<<<512, 256, 0, stream>>>(H, Wb, G, Q);

    dim3 g2(4, 32, 4);                // j-spans(512), i-tiles(64), batch
    k2_update<<<g2, 256, 0, stream>>>(Bp, G, Q, alpha, beta, out);
}